// Round 11
// baseline (1253.817 us; speedup 1.0000x reference)
//
#include <hip/hip_runtime.h>
#include <hip/hip_bf16.h>
#include <math.h>

#define NN 50000
#define EE 800000
#define KHALF 25000
#define NSAMP 1024
#define NBK (NSAMP+1)

typedef short bf16x8 __attribute__((ext_vector_type(8)));
typedef unsigned short us8 __attribute__((ext_vector_type(8)));
typedef unsigned short us4 __attribute__((ext_vector_type(4)));
typedef float f32x4 __attribute__((ext_vector_type(4)));

static __device__ inline unsigned short f2bf(float f){
  __hip_bfloat16 h = __float2bfloat16(f);
  return __builtin_bit_cast(unsigned short, h);
}
static __device__ inline float bf2f(unsigned short u){
  unsigned int x = ((unsigned int)u)<<16;
  return __builtin_bit_cast(float, x);
}

// ---------------- CSR build ----------------
__global__ void k_hist(const int* __restrict__ dst, int* __restrict__ cnt, int E){
  int i = blockIdx.x*blockDim.x + threadIdx.x;
  if(i<E) atomicAdd(&cnt[dst[i]], 1);
}

__global__ void k_scan(const int* __restrict__ deg, int* __restrict__ rowptr, int n){
  __shared__ int sm[1024];
  int t = threadIdx.x;
  int chunk = (n + 1023) >> 10;
  int b = t*chunk; int e = b+chunk; if(b>n) b=n; if(e>n) e=n;
  int s=0;
  for(int i=b;i<e;i++) s += deg[i];
  sm[t]=s; __syncthreads();
  for(int off=1; off<1024; off<<=1){
    int add = (t>=off)? sm[t-off] : 0;
    __syncthreads();
    sm[t] += add;
    __syncthreads();
  }
  int run = sm[t]-s;
  for(int i=b;i<e;i++){ rowptr[i]=run; run += deg[i]; }
  if(t==1023) rowptr[n]=sm[1023];
}

__global__ void k_fill(const int* __restrict__ src, const int* __restrict__ dst,
                       const int* __restrict__ rowptr, int* __restrict__ cnt,
                       int* __restrict__ csr, int E){
  int i = blockIdx.x*blockDim.x + threadIdx.x;
  if(i<E){
    int d = dst[i];
    int p = rowptr[d] + atomicAdd(&cnt[d],1);
    csr[p] = src[i];
  }
}

// ---------------- conv1 segmean (f64, bit-exact path) ----------------
template<typename AccT, typename OT, int F, int VW>
__global__ void k_segmean(const float* __restrict__ x, const int* __restrict__ csr,
                          const int* __restrict__ rowptr, OT* __restrict__ out, int n){
  int gid = blockIdx.x*blockDim.x + threadIdx.x;
  int node = gid >> 6; int lane = gid & 63;
  if(node>=n) return;
  int b = rowptr[node], e = rowptr[node+1];
  AccT acc[VW];
  #pragma unroll
  for(int k=0;k<VW;k++) acc[k]=(AccT)0;
  const float* xp = x + lane*VW;
  for(int j=b;j<e;j++){
    const float* row = xp + (long)csr[j]*F;
    acc[0] += (AccT)row[0];
  }
  int d = e-b; if(d<1) d=1;
  AccT inv = (AccT)1 / (AccT)d;
  out[(long)node*F + lane] = (OT)(acc[0]*inv);
}

// segmean over bf16 x1h rows -> A2 hi/lo planes (same f32 arithmetic as before)
__global__ void k_segmean_bfp(const unsigned short* __restrict__ xb,
                              const int* __restrict__ csr, const int* __restrict__ rowptr,
                              unsigned short* __restrict__ a2h, unsigned short* __restrict__ a2l,
                              int n){
  int gid = blockIdx.x*blockDim.x + threadIdx.x;
  int node = gid >> 6; int lane = gid & 63;
  if(node>=n) return;
  int b = rowptr[node], e = rowptr[node+1];
  float a0=0.f, a1=0.f;
  const unsigned short* xp = xb + lane*2;
  for(int j=b;j<e;j++){
    unsigned int u = *(const unsigned int*)(xp + (long)csr[j]*128);
    a0 += bf2f((unsigned short)(u & 0xffff));
    a1 += bf2f((unsigned short)(u >> 16));
  }
  int d=e-b; if(d<1)d=1;
  float inv = 1.f/(float)d;
  float rx = a0*inv, ry = a1*inv;
  unsigned short hx=f2bf(rx), hy=f2bf(ry);
  unsigned short lx=f2bf(rx-bf2f(hx)), ly=f2bf(ry-bf2f(hy));
  long o = (long)node*128 + lane*2;
  *(unsigned int*)(a2h + o) = (unsigned int)hx | ((unsigned int)hy<<16);
  *(unsigned int*)(a2l + o) = (unsigned int)lx | ((unsigned int)ly<<16);
}

// segmean(bf16 T3) + msr, split-written to mean/lstd
__global__ void k_segmean_ms(const unsigned short* __restrict__ T3,
                             const float* __restrict__ msr,
                             const int* __restrict__ csr, const int* __restrict__ rowptr,
                             float* __restrict__ omean, float* __restrict__ olstd, int n){
  int gid = blockIdx.x*blockDim.x + threadIdx.x;
  int node = gid >> 6; int lane = gid & 63;
  if(node>=n) return;
  int b = rowptr[node], e = rowptr[node+1];
  float a0=0.f, a1=0.f;
  const unsigned short* xp = T3 + lane*2;
  for(int j=b;j<e;j++){
    unsigned int u = *(const unsigned int*)(xp + (long)csr[j]*128);
    a0 += bf2f((unsigned short)(u & 0xffff));
    a1 += bf2f((unsigned short)(u >> 16));
  }
  int d=e-b; if(d<1)d=1;
  float inv = 1.f/(float)d;
  float2 mv = *(const float2*)(msr + (long)node*128 + lane*2);
  float2 r; r.x = a0*inv + mv.x; r.y = a1*inv + mv.y;
  int c0 = lane*2;
  if(c0 < 64) *(float2*)(omean + (long)node*64 + c0)      = r;
  else        *(float2*)(olstd + (long)node*64 + (c0-64)) = r;
}

// ---------------- pre-split staging (copy-only; values identical to old split) ----
static __device__ inline void stage_A_ps(const unsigned short* __restrict__ AH,
                                         const unsigned short* __restrict__ AL,
                                         int K, int k0, int m0, int M, int t,
                                         short* Ah, short* Al){
  #pragma unroll
  for(int i=0;i<4;i++){
    int f8 = t + i*256;
    int row = f8 >> 3, c8 = f8 & 7;
    int gr  = m0 + row;
    us8 vh = (us8){0,0,0,0,0,0,0,0};
    us8 vl = (us8){0,0,0,0,0,0,0,0};
    if(gr < M){
      long base = (long)gr*K + k0 + c8*8;
      vh = *(const us8*)(AH + base);
      vl = *(const us8*)(AL + base);
    }
    int byte = (row*128 + c8*16) ^ ((row&7)<<4);
    *(us8*)((char*)Ah + byte) = vh;
    *(us8*)((char*)Al + byte) = vl;
  }
}

static __device__ inline void stage_B_ps(const unsigned short* __restrict__ WH,
                                         const unsigned short* __restrict__ WL,
                                         int K, int k0, int n0, int t,
                                         short* Bh, short* Bl){
  int n = t & 63, k8 = (t>>6)<<3;
  #pragma unroll
  for(int i=0;i<2;i++){
    int kb = i*32 + k8;
    long base = (long)(n0+n)*K + k0 + kb;
    us8 vh = *(const us8*)(WH + base);
    us8 vl = *(const us8*)(WL + base);
    int byte = (n*128 + kb*2) ^ ((n&7)<<4);
    *(us8*)((char*)Bh + byte) = vh;
    *(us8*)((char*)Bl + byte) = vl;
  }
}

// ---------------- bf16x3 MFMA GEMM, pre-split operands ----------------
__global__ __launch_bounds__(256) void k_gemm_ps(
    const unsigned short* __restrict__ AH, const unsigned short* __restrict__ AL, int K1,
    const unsigned short* __restrict__ XH, const unsigned short* __restrict__ XL, int K2,
    const unsigned short* __restrict__ W1H, const unsigned short* __restrict__ W1L,
    const unsigned short* __restrict__ W2H, const unsigned short* __restrict__ W2L,
    const float* __restrict__ bias, float* __restrict__ out,
    int M, int J, int relu)
{
  __shared__ __align__(16) short Ah[128*64];
  __shared__ __align__(16) short Al[128*64];
  __shared__ __align__(16) short Bh[64*64];
  __shared__ __align__(16) short Bl[64*64];
  const int m0 = blockIdx.x*128, n0 = blockIdx.y*64;
  const int t = threadIdx.x;
  const int lane = t & 63, wid = t >> 6;
  const int wm = wid >> 1, wn = wid & 1;

  f32x4 acc[4][2];
  #pragma unroll
  for(int i=0;i<4;i++)
    #pragma unroll
    for(int j=0;j<2;j++) acc[i][j] = (f32x4){0.f,0.f,0.f,0.f};

  const int ns1 = K1 >> 6;
  const int ns2 = XH ? (K2 >> 6) : 0;
  for(int s=0; s<ns1+ns2; ++s){
    const unsigned short *PH, *PL, *WH, *WL; int K, k0;
    if(s < ns1){ PH=AH; PL=AL; K=K1; k0=s*64; WH=W1H; WL=W1L; }
    else       { PH=XH; PL=XL; K=K2; k0=(s-ns1)*64; WH=W2H; WL=W2L; }

    stage_A_ps(PH, PL, K, k0, m0, M, t, Ah, Al);
    stage_B_ps(WH, WL, K, k0, n0, t, Bh, Bl);
    __syncthreads();

    #pragma unroll
    for(int kk=0;kk<2;kk++){
      int kb = kk*32 + (lane>>4)*8;
      bf16x8 ahf[4], alf[4], bhf[2], blf[2];
      #pragma unroll
      for(int mf=0; mf<4; mf++){
        int r = wm*64 + mf*16 + (lane&15);
        int byte = (r*128 + kb*2) ^ ((r&7)<<4);
        ahf[mf] = *(const bf16x8*)((const char*)Ah + byte);
        alf[mf] = *(const bf16x8*)((const char*)Al + byte);
      }
      #pragma unroll
      for(int nf=0; nf<2; nf++){
        int n = wn*32 + nf*16 + (lane&15);
        int byte = (n*128 + kb*2) ^ ((n&7)<<4);
        bhf[nf] = *(const bf16x8*)((const char*)Bh + byte);
        blf[nf] = *(const bf16x8*)((const char*)Bl + byte);
      }
      #pragma unroll
      for(int mf=0; mf<4; mf++)
        #pragma unroll
        for(int nf=0; nf<2; nf++){
          acc[mf][nf] = __builtin_amdgcn_mfma_f32_16x16x32_bf16(ahf[mf], bhf[nf], acc[mf][nf], 0,0,0);
          acc[mf][nf] = __builtin_amdgcn_mfma_f32_16x16x32_bf16(ahf[mf], blf[nf], acc[mf][nf], 0,0,0);
          acc[mf][nf] = __builtin_amdgcn_mfma_f32_16x16x32_bf16(alf[mf], bhf[nf], acc[mf][nf], 0,0,0);
        }
    }
    __syncthreads();
  }

  #pragma unroll
  for(int mf=0; mf<4; mf++){
    #pragma unroll
    for(int nf=0; nf<2; nf++){
      int col = n0 + wn*32 + nf*16 + (lane&15);
      #pragma unroll
      for(int q=0;q<4;q++){
        int row = m0 + wm*64 + mf*16 + (lane>>4)*4 + q;
        if(row >= M) continue;
        float v = acc[mf][nf][q] + (bias ? bias[col] : 0.f);
        if(relu) v = fmaxf(v, 0.f);
        out[(long)row*J + col] = v;
      }
    }
  }
}

// merged conv3 (pre-split): grid (GX,4); y<2 -> Wa -> outa bf16; y>=2 -> Wb(+biasb) -> outb f32
__global__ __launch_bounds__(256) void k_gemm_ps2w(
    const unsigned short* __restrict__ AH, const unsigned short* __restrict__ AL, int K,
    const unsigned short* __restrict__ WaH, const unsigned short* __restrict__ WaL,
    const unsigned short* __restrict__ WbH, const unsigned short* __restrict__ WbL,
    const float* __restrict__ biasb,
    unsigned short* __restrict__ outa, float* __restrict__ outb, int M)
{
  __shared__ __align__(16) short Ah[128*64];
  __shared__ __align__(16) short Al[128*64];
  __shared__ __align__(16) short Bh[64*64];
  __shared__ __align__(16) short Bl[64*64];
  const bool sel = blockIdx.y >= 2;
  const unsigned short* WH = sel ? WbH : WaH;
  const unsigned short* WL = sel ? WbL : WaL;
  const int m0 = blockIdx.x*128, n0 = (blockIdx.y & 1)*64;
  const int t = threadIdx.x;
  const int lane = t & 63, wid = t >> 6;
  const int wm = wid >> 1, wn = wid & 1;

  f32x4 acc[4][2];
  #pragma unroll
  for(int i=0;i<4;i++)
    #pragma unroll
    for(int j=0;j<2;j++) acc[i][j] = (f32x4){0.f,0.f,0.f,0.f};

  const int ns = K >> 6;
  for(int s=0; s<ns; ++s){
    int k0 = s*64;
    stage_A_ps(AH, AL, K, k0, m0, M, t, Ah, Al);
    stage_B_ps(WH, WL, K, k0, n0, t, Bh, Bl);
    __syncthreads();

    #pragma unroll
    for(int kk=0;kk<2;kk++){
      int kb = kk*32 + (lane>>4)*8;
      bf16x8 ahf[4], alf[4], bhf[2], blf[2];
      #pragma unroll
      for(int mf=0; mf<4; mf++){
        int r = wm*64 + mf*16 + (lane&15);
        int byte = (r*128 + kb*2) ^ ((r&7)<<4);
        ahf[mf] = *(const bf16x8*)((const char*)Ah + byte);
        alf[mf] = *(const bf16x8*)((const char*)Al + byte);
      }
      #pragma unroll
      for(int nf=0; nf<2; nf++){
        int n = wn*32 + nf*16 + (lane&15);
        int byte = (n*128 + kb*2) ^ ((n&7)<<4);
        bhf[nf] = *(const bf16x8*)((const char*)Bh + byte);
        blf[nf] = *(const bf16x8*)((const char*)Bl + byte);
      }
      #pragma unroll
      for(int mf=0; mf<4; mf++)
        #pragma unroll
        for(int nf=0; nf<2; nf++){
          acc[mf][nf] = __builtin_amdgcn_mfma_f32_16x16x32_bf16(ahf[mf], bhf[nf], acc[mf][nf], 0,0,0);
          acc[mf][nf] = __builtin_amdgcn_mfma_f32_16x16x32_bf16(ahf[mf], blf[nf], acc[mf][nf], 0,0,0);
          acc[mf][nf] = __builtin_amdgcn_mfma_f32_16x16x32_bf16(alf[mf], bhf[nf], acc[mf][nf], 0,0,0);
        }
    }
    __syncthreads();
  }

  #pragma unroll
  for(int mf=0; mf<4; mf++){
    #pragma unroll
    for(int nf=0; nf<2; nf++){
      int col = n0 + wn*32 + nf*16 + (lane&15);
      #pragma unroll
      for(int q=0;q<4;q++){
        int row = m0 + wm*64 + mf*16 + (lane>>4)*4 + q;
        if(row >= M) continue;
        if(sel) outb[(long)row*128 + col] = acc[mf][nf][q] + biasb[col];
        else    outa[(long)row*128 + col] = f2bf(acc[mf][nf][q]);
      }
    }
  }
}

// ---------------- conv1 GEMM in f64 (score-critical path) -------------------
// R9 structure (conflict-free, bit-identical); launch_bounds 5 blocks/CU.
__global__ __launch_bounds__(256,5) void k_gemm_c1(
    const double* __restrict__ A1, const float* __restrict__ X,
    const float* __restrict__ W1, const float* __restrict__ W2,
    const float* __restrict__ bias, double* __restrict__ out, int M)
{
  __shared__ double Asd[32*67];
  __shared__ float  Wsf[32*66];
  const int m0 = blockIdx.x*64, n0 = blockIdx.y*64;
  const int t = threadIdx.x;
  const int tm = t & 15, tn = t >> 4;
  double acc[4][4];
  #pragma unroll
  for(int i=0;i<4;i++)
    #pragma unroll
    for(int j=0;j<4;j++) acc[i][j]=0.0;

  for(int pair=0; pair<2; pair++){
    const float* Wp = pair ? W2 : W1;
    for(int k0=0; k0<64; k0+=32){
      #pragma unroll
      for(int i=0;i<8;i++){
        int idx = t + i*256;
        int r = idx >> 5, c = idx & 31;
        int gr = m0 + r;
        double v = 0.0;
        if(gr<M) v = pair ? (double)X[(long)gr*64 + k0 + c] : A1[(long)gr*64 + k0 + c];
        Asd[c*67 + r] = v;
      }
      #pragma unroll
      for(int i=0;i<8;i++){
        int idx = t + i*256;
        int kk = idx >> 6, n = idx & 63;
        Wsf[kk*66 + n] = Wp[(k0+kk)*128 + n0 + n];
      }
      __syncthreads();
      #pragma unroll
      for(int kk=0;kk<32;kk++){
        double a0=Asd[kk*67 + tm],    a1=Asd[kk*67 + tm+16];
        double a2=Asd[kk*67 + tm+32], a3=Asd[kk*67 + tm+48];
        double w0=(double)Wsf[kk*66 + tn*4+0], w1=(double)Wsf[kk*66 + tn*4+1];
        double w2=(double)Wsf[kk*66 + tn*4+2], w3=(double)Wsf[kk*66 + tn*4+3];
        acc[0][0] += a0*w0; acc[0][1] += a0*w1; acc[0][2] += a0*w2; acc[0][3] += a0*w3;
        acc[1][0] += a1*w0; acc[1][1] += a1*w1; acc[1][2] += a1*w2; acc[1][3] += a1*w3;
        acc[2][0] += a2*w0; acc[2][1] += a2*w1; acc[2][2] += a2*w2; acc[2][3] += a2*w3;
        acc[3][0] += a3*w0; acc[3][1] += a3*w1; acc[3][2] += a3*w2; acc[3][3] += a3*w3;
      }
      __syncthreads();
    }
  }
  #pragma unroll
  for(int i=0;i<4;i++){
    int gr = m0 + tm + 16*i;
    if(gr>=M) continue;
    #pragma unroll
    for(int j=0;j<4;j++){
      int gc = n0 + tn*4 + j;
      double v = acc[i][j] + (double)bias[gc];
      if(v<0.0) v=0.0;
      out[(long)gr*128 + gc] = v;
    }
  }
}

// ---------------- weight fold / pre-split ----------------
__global__ void k_wfold(const float* __restrict__ Wt, const float* __restrict__ bt,
                        const float* __restrict__ Wd1, const float* __restrict__ bd1,
                        unsigned short* __restrict__ WcTh, unsigned short* __restrict__ WcTl,
                        float* __restrict__ bc){
  int j = threadIdx.x;   // 128
  int i = blockIdx.x;    // 0..128
  if(i < 128){
    float s = 0.f;
    for(int k=0;k<64;k++) s += Wt[i*64+k] * Wd1[(64+k)*128 + j];
    unsigned short h = f2bf(s);
    WcTh[j*128 + i] = h;
    WcTl[j*128 + i] = f2bf(s - bf2f(h));
  } else {
    float s = bd1[j];
    for(int k=0;k<64;k++) s += bt[k] * Wd1[(64+k)*128 + j];
    bc[j] = s;
  }
}

// pre-split + transpose one weight: plane[n*K + k] = split(W[k*J + n])
static __device__ inline void wsplit1(const float* __restrict__ W, int kshift, int J,
                                      unsigned short* __restrict__ oh,
                                      unsigned short* __restrict__ ol, int idx){
  int total = J << kshift;
  if(idx >= total) return;
  int K = 1 << kshift;
  int n = idx >> kshift, k = idx & (K-1);
  float v = W[k*J + n];
  unsigned short h = f2bf(v);
  oh[idx] = h;
  ol[idx] = f2bf(v - bf2f(h));
}

__global__ void k_wsplit(const float* We2l, const float* We2r,
                         const float* We3l, const float* We3r,
                         const float* Wd1, const float* Wd2,
                         unsigned short* e2lh, unsigned short* e2ll,
                         unsigned short* e2rh, unsigned short* e2rl,
                         unsigned short* e3lh, unsigned short* e3ll,
                         unsigned short* e3rh, unsigned short* e3rl,
                         unsigned short* d1h, unsigned short* d1l,
                         unsigned short* d2h, unsigned short* d2l){
  int idx = blockIdx.x*256 + threadIdx.x;
  switch(blockIdx.y){
    case 0: wsplit1(We2l, 7, 256, e2lh, e2ll, idx); break;
    case 1: wsplit1(We2r, 7, 256, e2rh, e2rl, idx); break;
    case 2: wsplit1(We3l, 8, 128, e3lh, e3ll, idx); break;
    case 3: wsplit1(We3r, 8, 128, e3rh, e3rl, idx); break;
    case 4: wsplit1(Wd1,  6, 128, d1h,  d1l,  idx); break;
    case 5: wsplit1(Wd2,  7, 64,  d2h,  d2l,  idx); break;
  }
}

// ---------------- batchnorm ----------------
template<typename T>
__global__ void k_colstats(const T* __restrict__ x, int M, int J,
                           double* __restrict__ ps, double* __restrict__ pq){
  int c = threadIdx.x; int b = blockIdx.x, B = gridDim.x;
  int rows = (M + B - 1)/B;
  int r0 = b*rows, r1 = r0+rows; if(r1>M) r1=M;
  double s=0.0,q=0.0;
  for(int r=r0;r<r1;r++){ double v = (double)x[(long)r*J + c]; s+=v; q+=v*v; }
  ps[(long)b*J+c]=s; pq[(long)b*J+c]=q;
}

__global__ void k_bnfinal(const double* __restrict__ ps, const double* __restrict__ pq,
                          int B, int J, int M, const float* __restrict__ g,
                          const float* __restrict__ bta,
                          double* __restrict__ sc, double* __restrict__ sh,
                          float* __restrict__ sc32, float* __restrict__ sh32){
  int c = threadIdx.x; if(c>=J) return;
  double s=0.0,q=0.0;
  for(int b=0;b<B;b++){ s+=ps[(long)b*J+c]; q+=pq[(long)b*J+c]; }
  double m = s/M; double v = q/M - m*m;
  double inv = 1.0/sqrt(v + 1e-5);
  double a = (double)g[c]*inv;
  sc[c]=a; sh[c]=(double)bta[c] - m*a;
  sc32[c]=(float)a; sh32[c]=(float)((double)bta[c] - m*a);
}

// BN-apply (f32, same math as old in-staging BN) + hi/lo split
__global__ void k_bnsplit(const float* __restrict__ x, const float* __restrict__ sc,
                          const float* __restrict__ sh,
                          unsigned short* __restrict__ oh, unsigned short* __restrict__ ol,
                          int total4, int Jm){
  int i = blockIdx.x*256 + threadIdx.x;
  if(i>=total4) return;
  float4 v = ((const float4*)x)[i];
  int c = (i*4) & Jm;
  v.x = v.x*sc[c]   + sh[c];
  v.y = v.y*sc[c+1] + sh[c+1];
  v.z = v.z*sc[c+2] + sh[c+2];
  v.w = v.w*sc[c+3] + sh[c+3];
  unsigned short h0=f2bf(v.x), h1=f2bf(v.y), h2=f2bf(v.z), h3=f2bf(v.w);
  us4 hi = (us4){h0,h1,h2,h3};
  us4 lo = (us4){f2bf(v.x-bf2f(h0)), f2bf(v.y-bf2f(h1)),
                 f2bf(v.z-bf2f(h2)), f2bf(v.w-bf2f(h3))};
  ((us4*)oh)[i] = hi;
  ((us4*)ol)[i] = lo;
}

// fused BN-apply + pooling dot terms + x1 hi/lo planes (wave per node)
__global__ void k_bntr(const double* __restrict__ xp,
                       const double* __restrict__ sc, const double* __restrict__ sh,
                       const float* __restrict__ wrel, const float* __restrict__ wroot,
                       float* __restrict__ o32,
                       unsigned short* __restrict__ x1h, unsigned short* __restrict__ x1l,
                       double* __restrict__ t, double* __restrict__ r, int n){
  int gid = blockIdx.x*blockDim.x + threadIdx.x;
  int node = gid>>6, lane = gid&63;
  if(node>=n) return;
  long base = (long)node*128;
  double v0 = xp[base+lane]   *sc[lane]    + sh[lane];
  double v1 = xp[base+lane+64]*sc[lane+64] + sh[lane+64];
  float f0 = (float)v0, f1 = (float)v1;
  o32[base+lane]    = f0;
  o32[base+lane+64] = f1;
  unsigned short h0 = f2bf(f0), h1 = f2bf(f1);
  x1h[base+lane]    = h0;
  x1h[base+lane+64] = h1;
  x1l[base+lane]    = f2bf(f0 - bf2f(h0));
  x1l[base+lane+64] = f2bf(f1 - bf2f(h1));
  double tv = v0*(double)wrel[lane]  + v1*(double)wrel[lane+64];
  double rv = v0*(double)wroot[lane] + v1*(double)wroot[lane+64];
  for(int off=32; off>0; off>>=1){
    tv += __shfl_xor(tv, off);
    rv += __shfl_xor(rv, off);
  }
  if(lane==0){ t[node]=tv; r[node]=rv; }
}

// ---------------- z = mean + exp(log_std)*noise.mean(0) -> hi/lo planes -------
__global__ void k_z(const float* __restrict__ mean, const float* __restrict__ lstd,
                    const float* __restrict__ noise,
                    unsigned short* __restrict__ zh, unsigned short* __restrict__ zl,
                    int total4){
  int i = blockIdx.x*blockDim.x + threadIdx.x;
  if(i>=total4) return;
  const float4* m4 = (const float4*)mean;
  const float4* l4 = (const float4*)lstd;
  const float4* n4 = (const float4*)noise;
  float4 m = m4[i], l = l4[i];
  float nx=0.f, ny=0.f, nz=0.f, nw=0.f;
  #pragma unroll
  for(int s=0;s<10;s++){
    float4 v = n4[(long)s*total4 + i];
    nx+=v.x; ny+=v.y; nz+=v.z; nw+=v.w;
  }
  float o0 = (float)((double)m.x + exp((double)l.x)*((double)nx*0.1));
  float o1 = (float)((double)m.y + exp((double)l.y)*((double)ny*0.1));
  float o2 = (float)((double)m.z + exp((double)l.z)*((double)nz*0.1));
  float o3 = (float)((double)m.w + exp((double)l.w)*((double)nw*0.1));
  unsigned short h0=f2bf(o0), h1=f2bf(o1), h2=f2bf(o2), h3=f2bf(o3);
  us4 hi = (us4){h0,h1,h2,h3};
  us4 lo = (us4){f2bf(o0-bf2f(h0)), f2bf(o1-bf2f(h1)),
                 f2bf(o2-bf2f(h2)), f2bf(o3-bf2f(h3))};
  ((us4*)zh)[i] = hi;
  ((us4*)zl)[i] = lo;
}

__global__ void k_score(const double* __restrict__ t, const double* __restrict__ r,
                        const int* __restrict__ csr, const int* __restrict__ rowptr,
                        const float* __restrict__ bp,
                        unsigned long long* __restrict__ key, int n){
  int i = blockIdx.x*blockDim.x + threadIdx.x;
  if(i>=n) return;
  double s = (double)bp[0] + r[i];
  int b=rowptr[i], e=rowptr[i+1];
  for(int j=b;j<e;j++) s += t[csr[j]];
  double sc = tanh(s) + 0.0;           // -0 -> +0
  long long u = __double_as_longlong(sc);
  unsigned long long uu = (unsigned long long)u;
  key[i] = (u < 0) ? ~uu : (uu ^ 0x8000000000000000ULL);
}

// ---- splitter-bucketed exact rank ----
__global__ void k_sample_sort(const unsigned long long* __restrict__ key,
                              unsigned long long* __restrict__ samp){
  __shared__ unsigned long long sm[NSAMP];
  int t = threadIdx.x;
  sm[t] = key[t*48];
  __syncthreads();
  for(int k=2; k<=NSAMP; k<<=1){
    for(int j=k>>1; j>0; j>>=1){
      int l = t ^ j;
      if(l > t){
        unsigned long long a = sm[t], b = sm[l];
        bool up = ((t & k) == 0);
        if(up ? (a > b) : (a < b)){ sm[t]=b; sm[l]=a; }
      }
      __syncthreads();
    }
  }
  samp[t] = sm[t];
}

__global__ __launch_bounds__(256) void k_bucket_assign(
    const unsigned long long* __restrict__ key,
    const unsigned long long* __restrict__ samp,
    int* __restrict__ bucket, int* __restrict__ bcnt, int n){
  __shared__ unsigned long long sm[NSAMP];
  for(int u=threadIdx.x; u<NSAMP; u+=256) sm[u] = samp[u];
  __syncthreads();
  int i = blockIdx.x*256 + threadIdx.x;
  if(i>=n) return;
  unsigned long long ki = key[i];
  int lo=0, hi=NSAMP;
  while(lo<hi){ int mid=(lo+hi)>>1; if(sm[mid] < ki) lo=mid+1; else hi=mid; }
  bucket[i]=lo;
  atomicAdd(&bcnt[lo],1);
}

__global__ void k_bucket_fill(const int* __restrict__ bucket,
                              const int* __restrict__ bstart, int* __restrict__ bfill,
                              int* __restrict__ blist, int n){
  int i = blockIdx.x*blockDim.x + threadIdx.x;
  if(i>=n) return;
  int b = bucket[i];
  int p = bstart[b] + atomicAdd(&bfill[b],1);
  blist[p] = i;
}

__global__ __launch_bounds__(256) void k_bucket_rank(
    const unsigned long long* __restrict__ key,
    const int* __restrict__ blist, const int* __restrict__ bstart,
    int n, int k, int* __restrict__ keep, int* __restrict__ perm){
  __shared__ unsigned long long skey[2048];
  __shared__ int sidx[2048];
  int b = blockIdx.x;
  int s0 = bstart[b], s1 = bstart[b+1];
  int m = s1 - s0;
  if(m<=0) return;
  int above = n - s1;
  if(m <= 2048){
    for(int u=threadIdx.x; u<m; u+=256){ int ii=blist[s0+u]; sidx[u]=ii; skey[u]=key[ii]; }
    __syncthreads();
    for(int u=threadIdx.x; u<m; u+=256){
      unsigned long long ki = skey[u]; int ii = sidx[u];
      int c = 0;
      for(int v=0; v<m; v++){
        unsigned long long kv = skey[v];
        c += ((kv > ki) || (kv == ki && sidx[v] < ii)) ? 1 : 0;
      }
      int rank = above + c;
      int kp = (rank < k) ? 1 : 0;
      keep[ii] = kp;
      if(kp) perm[rank] = ii;
    }
  } else {
    for(int u=threadIdx.x; u<m; u+=256){
      int ii = blist[s0+u];
      unsigned long long ki = key[ii];
      int c=0;
      for(int v=0; v<m; v++){
        int jj = blist[s0+v];
        unsigned long long kv = key[jj];
        c += ((kv > ki) || (kv == ki && jj < ii)) ? 1 : 0;
      }
      int rank = above + c;
      int kp = (rank < k) ? 1 : 0;
      keep[ii] = kp;
      if(kp) perm[rank] = ii;
    }
  }
}

__global__ void k_unpool(const float* __restrict__ x1, const int* __restrict__ perm,
                         float* __restrict__ out, int k){
  int i = blockIdx.x*blockDim.x + threadIdx.x;
  if(i >= k*128) return;
  int r = i>>7, c = i&127;
  out[i] = x1[(long)perm[r]*128 + c];
}

__global__ void k_edgeout(const int* __restrict__ src, const int* __restrict__ dst,
                          const int* __restrict__ keep, float* __restrict__ o2,
                          float* __restrict__ o3, int E){
  int e = blockIdx.x*blockDim.x + threadIdx.x;
  if(e>=E) return;
  int s=src[e], d=dst[e];
  bool m = keep[s] && keep[d];
  o2[e]   = m ? (float)s : -1.f;
  o2[E+e] = m ? (float)d : -1.f;
  o3[e]   = m ? 1.f : 0.f;
}

// ---------------- launch ----------------
extern "C" void kernel_launch(void* const* d_in, const int* in_sizes, int n_in,
                              void* d_out, int out_size, void* d_ws, size_t ws_size,
                              hipStream_t stream){
  const float* x     = (const float*)d_in[0];
  const int*   ei    = (const int*)d_in[1];
  const float* noise = (const float*)d_in[3];
  const float* We1l  = (const float*)d_in[4];
  const float* be1   = (const float*)d_in[5];
  const float* We1r  = (const float*)d_in[6];
  const float* g1    = (const float*)d_in[7];
  const float* b1    = (const float*)d_in[8];
  const float* We2l  = (const float*)d_in[9];
  const float* be2   = (const float*)d_in[10];
  const float* We2r  = (const float*)d_in[11];
  const float* g2    = (const float*)d_in[12];
  const float* b2    = (const float*)d_in[13];
  const float* We3l  = (const float*)d_in[14];
  const float* be3   = (const float*)d_in[15];
  const float* We3r  = (const float*)d_in[16];
  const float* Wt    = (const float*)d_in[17];
  const float* bt    = (const float*)d_in[18];
  const float* Wd1   = (const float*)d_in[19];
  const float* bd1   = (const float*)d_in[20];
  const float* gd    = (const float*)d_in[21];
  const float* bd    = (const float*)d_in[22];
  const float* Wd2   = (const float*)d_in[23];
  const float* bd2   = (const float*)d_in[24];
  const float* Wprel = (const float*)d_in[25];
  const float* bp    = (const float*)d_in[26];
  const float* Wproot= (const float*)d_in[27];

  const int* src = ei;
  const int* dst = ei + EE;

  float* out   = (float*)d_out;
  float* o_rec  = out;                 // N*64
  float* o_xun  = out + 3200000;       // k*128
  float* o_eiu  = out + 6400000;       // 2*E
  float* o_mask = out + 8000000;       // E
  float* o_mean = out + 8800000;       // N*64
  float* o_lstd = out + 12000000;      // N*64
  float* o_x1   = out + 15200000;      // N*128

  char* w = (char*)d_ws;
  size_t off = 0;
  auto alloc = [&](size_t bytes)->char*{
    char* p = w + off; off += (bytes + 255) & ~(size_t)255; return p;
  };
  int*    csr  = (int*)   alloc((size_t)EE*4);
  int*    rowp = (int*)   alloc((size_t)(NN+1)*4);
  int*    cnt  = (int*)   alloc((size_t)NN*4);
  char*   B3   =          alloc((size_t)NN*128*8);   // x1p f64 -> x2 f32 -> T3|msr -> h f32
  char*   B4   =          alloc((size_t)NN*64*8);    // A1 f64 -> a2h|a2l -> hh|hl
  char*   B5   =          alloc((size_t)NN*256*4);   // x2h|x2l -> zh|zl
  unsigned short* x1h = (unsigned short*)alloc((size_t)NN*128*2);
  unsigned short* x1l = (unsigned short*)alloc((size_t)NN*128*2);
  double* t_   = (double*)alloc((size_t)NN*8);
  double* r_   = (double*)alloc((size_t)NN*8);
  unsigned long long* key_ = (unsigned long long*)alloc((size_t)NN*8);
  int*    keep = (int*)   alloc((size_t)NN*4);
  int*    perm = (int*)   alloc((size_t)KHALF*4);
  double* ps   = (double*)alloc((size_t)240*256*8);
  double* pq   = (double*)alloc((size_t)240*256*8);
  double* bnsc = (double*)alloc(256*8);
  double* bnsh = (double*)alloc(256*8);
  float*  sc1f = (float*) alloc(256*4);
  float*  sh1f = (float*) alloc(256*4);
  float*  sc2f = (float*) alloc(256*4);
  float*  sh2f = (float*) alloc(256*4);
  float*  scdf = (float*) alloc(256*4);
  float*  shdf = (float*) alloc(256*4);
  unsigned short* WcTh = (unsigned short*)alloc(128*128*2);
  unsigned short* WcTl = (unsigned short*)alloc(128*128*2);
  float*  bc   = (float*) alloc(128*4);
  unsigned short* e2lh = (unsigned short*)alloc(128*256*2);
  unsigned short* e2ll = (unsigned short*)alloc(128*256*2);
  unsigned short* e2rh = (unsigned short*)alloc(128*256*2);
  unsigned short* e2rl = (unsigned short*)alloc(128*256*2);
  unsigned short* e3lh = (unsigned short*)alloc(256*128*2);
  unsigned short* e3ll = (unsigned short*)alloc(256*128*2);
  unsigned short* e3rh = (unsigned short*)alloc(256*128*2);
  unsigned short* e3rl = (unsigned short*)alloc(256*128*2);
  unsigned short* d1h  = (unsigned short*)alloc(64*128*2);
  unsigned short* d1l  = (unsigned short*)alloc(64*128*2);
  unsigned short* d2h  = (unsigned short*)alloc(128*64*2);
  unsigned short* d2l  = (unsigned short*)alloc(128*64*2);
  unsigned long long* samp = (unsigned long long*)alloc((size_t)NSAMP*8);
  int*    bucket = (int*) alloc((size_t)NN*4);
  int*    bcnt   = (int*) alloc((size_t)NBK*4);
  int*    bstart = (int*) alloc((size_t)(NBK+1)*4);
  int*    bfill  = (int*) alloc((size_t)NBK*4);
  int*    blist  = (int*) alloc((size_t)NN*4);
  (void)in_sizes; (void)n_in; (void)out_size; (void)ws_size;

  double* A1  = (double*)B4;
  unsigned short* a2h = (unsigned short*)B4;
  unsigned short* a2l = a2h + (size_t)NN*128;
  unsigned short* hh  = (unsigned short*)B4;
  unsigned short* hl  = hh + (size_t)NN*128;
  double* x1p = (double*)B3;
  float*  x2  = (float*)B3;
  unsigned short* T3 = (unsigned short*)B3;
  float*  msr = (float*)(B3 + (size_t)NN*128*2);
  float*  h   = (float*)B3;
  unsigned short* x2h = (unsigned short*)B5;
  unsigned short* x2l = x2h + (size_t)NN*256;
  unsigned short* zh  = (unsigned short*)B5;
  unsigned short* zl  = zh + (size_t)NN*64;

  const int GX = (NN+127)/128;   // 391

  // CSR build + weight fold/split (independent)
  hipMemsetAsync(cnt, 0, (size_t)NN*4, stream);
  k_hist<<<(EE+255)/256,256,0,stream>>>(dst, cnt, EE);
  k_wfold<<<129,128,0,stream>>>(Wt, bt, Wd1, bd1, WcTh, WcTl, bc);
  { dim3 g(128, 6);
    k_wsplit<<<g,256,0,stream>>>(We2l, We2r, We3l, We3r, Wd1, Wd2,
                                 e2lh,e2ll, e2rh,e2rl, e3lh,e3ll, e3rh,e3rl,
                                 d1h,d1l, d2h,d2l); }
  k_scan<<<1,1024,0,stream>>>(cnt, rowp, NN);
  hipMemsetAsync(cnt, 0, (size_t)NN*4, stream);
  k_fill<<<(EE+255)/256,256,0,stream>>>(src, dst, rowp, cnt, csr, EE);

  // conv1 (f64 score-critical path; bit-identical arithmetic)
  k_segmean<double,double,64,1><<<(NN+3)/4,256,0,stream>>>(x, csr, rowp, A1, NN);
  { dim3 g((NN+63)/64, 2);
    k_gemm_c1<<<g,256,0,stream>>>(A1, x, We1l, We1r, be1, x1p, NN); }
  k_colstats<double><<<240,128,0,stream>>>(x1p, NN, 128, ps, pq);
  k_bnfinal<<<1,128,0,stream>>>(ps,pq,240,128,NN,g1,b1,bnsc,bnsh,sc1f,sh1f);
  k_bntr<<<(NN+3)/4,256,0,stream>>>(x1p, bnsc, bnsh, Wprel, Wproot, o_x1, x1h, x1l, t_, r_, NN);

  // conv2: A2 planes from bf16 gather; GEMM consumes pre-split planes
  k_segmean_bfp<<<(NN+3)/4,256,0,stream>>>(x1h, csr, rowp, a2h, a2l, NN);
  { dim3 g(GX, 4);
    k_gemm_ps<<<g,256,0,stream>>>(a2h,a2l,128, x1h,x1l,128,
                                  e2lh,e2ll, e2rh,e2rl, be2, x2, NN, 256, 1); }
  k_colstats<float><<<240,256,0,stream>>>(x2, NN, 256, ps, pq);
  k_bnfinal<<<1,256,0,stream>>>(ps,pq,240,256,NN,g2,b2,bnsc,bnsh,sc2f,sh2f);

  // conv3: BN+split once, merged dual-weight GEMM; T3 bf16 + msr f32
  k_bnsplit<<<(3200000+255)/256,256,0,stream>>>(x2, sc2f, sh2f, x2h, x2l, 3200000, 255);
  { dim3 g(GX, 4);
    k_gemm_ps2w<<<g,256,0,stream>>>(x2h,x2l,256, e3lh,e3ll, e3rh,e3rl, be3, T3, msr, NN); }
  k_segmean_ms<<<(NN+3)/4,256,0,stream>>>(T3, msr, csr, rowp, o_mean, o_lstd, NN);

  // decoder: z planes, fused h = relu(z@Wd1_top + x1@Wc + bc)
  k_z<<<(800000+255)/256,256,0,stream>>>(o_mean, o_lstd, noise, zh, zl, 800000);
  { dim3 g(GX, 2);
    k_gemm_ps<<<g,256,0,stream>>>(zh,zl,64, x1h,x1l,128,
                                  d1h,d1l, WcTh,WcTl, bc, h, NN, 128, 1); }
  k_colstats<float><<<240,128,0,stream>>>(h, NN, 128, ps, pq);
  k_bnfinal<<<1,128,0,stream>>>(ps,pq,240,128,NN,gd,bd,bnsc,bnsh,scdf,shdf);
  k_bnsplit<<<(1600000+255)/256,256,0,stream>>>(h, scdf, shdf, hh, hl, 1600000, 127);
  { dim3 g(GX, 1);
    k_gemm_ps<<<g,256,0,stream>>>(hh,hl,128, nullptr,nullptr,0,
                                  d2h,d2l, nullptr,nullptr, bd2, o_rec, NN, 64, 0); }

  // pooling: score/key -> splitter-bucketed exact rank -> outputs
  k_score<<<(NN+255)/256,256,0,stream>>>(t_, r_, csr, rowp, bp, key_, NN);
  k_sample_sort<<<1,1024,0,stream>>>(key_, samp);
  hipMemsetAsync(bcnt, 0, (size_t)NBK*4, stream);
  k_bucket_assign<<<(NN+255)/256,256,0,stream>>>(key_, samp, bucket, bcnt, NN);
  k_scan<<<1,1024,0,stream>>>(bcnt, bstart, NBK);
  hipMemsetAsync(bfill, 0, (size_t)NBK*4, stream);
  k_bucket_fill<<<(NN+255)/256,256,0,stream>>>(bucket, bstart, bfill, blist, NN);
  k_bucket_rank<<<NBK,256,0,stream>>>(key_, blist, bstart, NN, KHALF, keep, perm);
  k_unpool<<<(KHALF*128+255)/256,256,0,stream>>>(o_x1, perm, o_xun, KHALF);
  k_edgeout<<<(EE+255)/256,256,0,stream>>>(src, dst, keep, o_eiu, o_mask, EE);
}

// Round 13
// 1219.975 us; speedup vs baseline: 1.0277x; 1.0277x over previous
//
#include <hip/hip_runtime.h>
#include <hip/hip_bf16.h>
#include <math.h>

#define NN 50000
#define EE 800000
#define KHALF 25000
#define NSAMP 1024
#define NBK (NSAMP+1)

typedef short bf16x8 __attribute__((ext_vector_type(8)));
typedef short sh4 __attribute__((ext_vector_type(4)));
typedef float f32x4 __attribute__((ext_vector_type(4)));

static __device__ inline unsigned short f2bf(float f){
  __hip_bfloat16 h = __float2bfloat16(f);
  return __builtin_bit_cast(unsigned short, h);
}
static __device__ inline float bf2f(unsigned short u){
  unsigned int x = ((unsigned int)u)<<16;
  return __builtin_bit_cast(float, x);
}

// ---------------- CSR build ----------------
__global__ void k_hist(const int* __restrict__ dst, int* __restrict__ cnt, int E){
  int i = blockIdx.x*blockDim.x + threadIdx.x;
  if(i<E) atomicAdd(&cnt[dst[i]], 1);
}

__global__ void k_scan(const int* __restrict__ deg, int* __restrict__ rowptr, int n){
  __shared__ int sm[1024];
  int t = threadIdx.x;
  int chunk = (n + 1023) >> 10;
  int b = t*chunk; int e = b+chunk; if(b>n) b=n; if(e>n) e=n;
  int s=0;
  for(int i=b;i<e;i++) s += deg[i];
  sm[t]=s; __syncthreads();
  for(int off=1; off<1024; off<<=1){
    int add = (t>=off)? sm[t-off] : 0;
    __syncthreads();
    sm[t] += add;
    __syncthreads();
  }
  int run = sm[t]-s;
  for(int i=b;i<e;i++){ rowptr[i]=run; run += deg[i]; }
  if(t==1023) rowptr[n]=sm[1023];
}

__global__ void k_fill(const int* __restrict__ src, const int* __restrict__ dst,
                       const int* __restrict__ rowptr, int* __restrict__ cnt,
                       int* __restrict__ csr, int E){
  int i = blockIdx.x*blockDim.x + threadIdx.x;
  if(i<E){
    int d = dst[i];
    int p = rowptr[d] + atomicAdd(&cnt[d],1);
    csr[p] = src[i];
  }
}

// ---------------- segment mean (wave per node, vectorized gather) ----------------
template<typename AccT, typename OT, int F, int VW>
__global__ void k_segmean(const float* __restrict__ x, const int* __restrict__ csr,
                          const int* __restrict__ rowptr, OT* __restrict__ out, int n){
  int gid = blockIdx.x*blockDim.x + threadIdx.x;
  int node = gid >> 6; int lane = gid & 63;
  if(node>=n) return;
  int b = rowptr[node], e = rowptr[node+1];
  AccT acc[VW];
  #pragma unroll
  for(int k=0;k<VW;k++) acc[k]=(AccT)0;
  const float* xp = x + lane*VW;
  for(int j=b;j<e;j++){
    const float* row = xp + (long)csr[j]*F;
    if(VW==1){
      acc[0] += (AccT)row[0];
    } else if(VW==2){
      float2 v = *(const float2*)row;
      acc[0]+=(AccT)v.x; acc[1]+=(AccT)v.y;
    } else {
      float4 v = *(const float4*)row;
      acc[0]+=(AccT)v.x; acc[1]+=(AccT)v.y; acc[2]+=(AccT)v.z; acc[3]+=(AccT)v.w;
    }
  }
  int d = e-b; if(d<1) d=1;
  AccT inv = (AccT)1 / (AccT)d;
  #pragma unroll
  for(int k=0;k<VW;k++) out[(long)node*F + lane*VW + k] = (OT)(acc[k]*inv);
}

// segmean over bf16 rows (F=128): lane covers cols {2*lane, 2*lane+1}, 4B/lane
__global__ void k_segmean_bf(const unsigned short* __restrict__ xb,
                             const int* __restrict__ csr, const int* __restrict__ rowptr,
                             float* __restrict__ out, int n){
  int gid = blockIdx.x*blockDim.x + threadIdx.x;
  int node = gid >> 6; int lane = gid & 63;
  if(node>=n) return;
  int b = rowptr[node], e = rowptr[node+1];
  float a0=0.f, a1=0.f;
  const unsigned short* xp = xb + lane*2;
  for(int j=b;j<e;j++){
    unsigned int u = *(const unsigned int*)(xp + (long)csr[j]*128);
    a0 += bf2f((unsigned short)(u & 0xffff));
    a1 += bf2f((unsigned short)(u >> 16));
  }
  int d=e-b; if(d<1)d=1;
  float inv = 1.f/(float)d;
  float2 r; r.x=a0*inv; r.y=a1*inv;
  *(float2*)(out + (long)node*128 + lane*2) = r;
}

// segmean(bf16 T3) + msr, split-written to mean/lstd
__global__ void k_segmean_ms(const unsigned short* __restrict__ T3,
                             const float* __restrict__ msr,
                             const int* __restrict__ csr, const int* __restrict__ rowptr,
                             float* __restrict__ omean, float* __restrict__ olstd, int n){
  int gid = blockIdx.x*blockDim.x + threadIdx.x;
  int node = gid >> 6; int lane = gid & 63;
  if(node>=n) return;
  int b = rowptr[node], e = rowptr[node+1];
  float a0=0.f, a1=0.f;
  const unsigned short* xp = T3 + lane*2;
  for(int j=b;j<e;j++){
    unsigned int u = *(const unsigned int*)(xp + (long)csr[j]*128);
    a0 += bf2f((unsigned short)(u & 0xffff));
    a1 += bf2f((unsigned short)(u >> 16));
  }
  int d=e-b; if(d<1)d=1;
  float inv = 1.f/(float)d;
  float2 mv = *(const float2*)(msr + (long)node*128 + lane*2);
  float2 r; r.x = a0*inv + mv.x; r.y = a1*inv + mv.y;
  int c0 = lane*2;
  if(c0 < 64) *(float2*)(omean + (long)node*64 + c0)      = r;
  else        *(float2*)(olstd + (long)node*64 + (c0-64)) = r;
}

// ---------------- bf16x3 staging helpers ----------------
static __device__ inline void stage_A_bf16(const float* __restrict__ P, int K, int k0,
                                           int m0, int M, int t,
                                           const float* __restrict__ bnsc,
                                           const float* __restrict__ bnsh,
                                           short* Ah, short* Al, bool bn){
  #pragma unroll
  for(int i=0;i<8;i++){
    int f4  = t + i*256;
    int row = f4 >> 4, c4 = f4 & 15;
    int gr  = m0 + row;
    float4 v = make_float4(0.f,0.f,0.f,0.f);
    if(gr < M) v = *(const float4*)(P + (long)gr*K + k0 + c4*4);
    if(bn){
      int kc = k0 + c4*4;
      v.x = v.x*bnsc[kc]   + bnsh[kc];
      v.y = v.y*bnsc[kc+1] + bnsh[kc+1];
      v.z = v.z*bnsc[kc+2] + bnsh[kc+2];
      v.w = v.w*bnsc[kc+3] + bnsh[kc+3];
    }
    unsigned short h0=f2bf(v.x), h1=f2bf(v.y), h2=f2bf(v.z), h3=f2bf(v.w);
    sh4 hi = (sh4){(short)h0,(short)h1,(short)h2,(short)h3};
    sh4 lo = (sh4){(short)f2bf(v.x-bf2f(h0)), (short)f2bf(v.y-bf2f(h1)),
                   (short)f2bf(v.z-bf2f(h2)), (short)f2bf(v.w-bf2f(h3))};
    int byte = (row*128 + c4*8) ^ ((row&7)<<4);
    *(sh4*)((char*)Ah + byte) = hi;
    *(sh4*)((char*)Al + byte) = lo;
  }
}

static __device__ inline void stage_B_bf16(const float* __restrict__ W, int J, int k0,
                                           int n0, int t, short* Bh, short* Bl){
  int n = t & 63, k4 = (t>>6)<<2;
  #pragma unroll
  for(int i=0;i<4;i++){
    int kb = i*16 + k4;
    const float* wp = W + (long)(k0+kb)*J + n0 + n;
    float w0 = wp[0], w1 = wp[J], w2 = wp[2*J], w3 = wp[3*J];
    unsigned short h0=f2bf(w0), h1=f2bf(w1), h2=f2bf(w2), h3=f2bf(w3);
    sh4 hi = (sh4){(short)h0,(short)h1,(short)h2,(short)h3};
    sh4 lo = (sh4){(short)f2bf(w0-bf2f(h0)), (short)f2bf(w1-bf2f(h1)),
                   (short)f2bf(w2-bf2f(h2)), (short)f2bf(w3-bf2f(h3))};
    int byte = (n*128 + kb*2) ^ ((n&7)<<4);
    *(sh4*)((char*)Bh + byte) = hi;
    *(sh4*)((char*)Bl + byte) = lo;
  }
}

// ---------------- bf16x3-split MFMA GEMM (optional fused BN on A-operand) ----
__global__ __launch_bounds__(256) void k_gemm_bf16s(
    const float* __restrict__ A, const float* __restrict__ W1, int K1,
    const float* __restrict__ X, const float* __restrict__ W2, int K2,
    const float* __restrict__ bias, float* __restrict__ out,
    int M, int J, int relu,
    const float* __restrict__ bnsc, const float* __restrict__ bnsh)
{
  __shared__ __align__(16) short Ah[128*64];
  __shared__ __align__(16) short Al[128*64];
  __shared__ __align__(16) short Bh[64*64];
  __shared__ __align__(16) short Bl[64*64];
  const int m0 = blockIdx.x*128, n0 = blockIdx.y*64;
  const int t = threadIdx.x;
  const int lane = t & 63, wid = t >> 6;
  const int wm = wid >> 1, wn = wid & 1;

  f32x4 acc[4][2];
  #pragma unroll
  for(int i=0;i<4;i++)
    #pragma unroll
    for(int j=0;j<2;j++) acc[i][j] = (f32x4){0.f,0.f,0.f,0.f};

  const int ns1 = K1 >> 6;
  const int ns2 = X ? (K2 >> 6) : 0;
  for(int s=0; s<ns1+ns2; ++s){
    const float* P; const float* W; int K, k0;
    if(s < ns1){ P = A; W = W1; K = K1; k0 = s*64; }
    else       { P = X; W = W2; K = K2; k0 = (s-ns1)*64; }
    const bool bn = (bnsc != nullptr) && (s < ns1);

    stage_A_bf16(P, K, k0, m0, M, t, bnsc, bnsh, Ah, Al, bn);
    stage_B_bf16(W, J, k0, n0, t, Bh, Bl);
    __syncthreads();

    #pragma unroll
    for(int kk=0;kk<2;kk++){
      int kb = kk*32 + (lane>>4)*8;
      bf16x8 ahf[4], alf[4], bhf[2], blf[2];
      #pragma unroll
      for(int mf=0; mf<4; mf++){
        int r = wm*64 + mf*16 + (lane&15);
        int byte = (r*128 + kb*2) ^ ((r&7)<<4);
        ahf[mf] = *(const bf16x8*)((const char*)Ah + byte);
        alf[mf] = *(const bf16x8*)((const char*)Al + byte);
      }
      #pragma unroll
      for(int nf=0; nf<2; nf++){
        int n = wn*32 + nf*16 + (lane&15);
        int byte = (n*128 + kb*2) ^ ((n&7)<<4);
        bhf[nf] = *(const bf16x8*)((const char*)Bh + byte);
        blf[nf] = *(const bf16x8*)((const char*)Bl + byte);
      }
      #pragma unroll
      for(int mf=0; mf<4; mf++)
        #pragma unroll
        for(int nf=0; nf<2; nf++){
          acc[mf][nf] = __builtin_amdgcn_mfma_f32_16x16x32_bf16(ahf[mf], bhf[nf], acc[mf][nf], 0,0,0);
          acc[mf][nf] = __builtin_amdgcn_mfma_f32_16x16x32_bf16(ahf[mf], blf[nf], acc[mf][nf], 0,0,0);
          acc[mf][nf] = __builtin_amdgcn_mfma_f32_16x16x32_bf16(alf[mf], bhf[nf], acc[mf][nf], 0,0,0);
        }
    }
    __syncthreads();
  }

  #pragma unroll
  for(int mf=0; mf<4; mf++){
    #pragma unroll
    for(int nf=0; nf<2; nf++){
      int col = n0 + wn*32 + nf*16 + (lane&15);
      #pragma unroll
      for(int q=0;q<4;q++){
        int row = m0 + wm*64 + mf*16 + (lane>>4)*4 + q;
        if(row >= M) continue;
        float v = acc[mf][nf][q] + (bias ? bias[col] : 0.f);
        if(relu) v = fmaxf(v, 0.f);
        out[(long)row*J + col] = v;
      }
    }
  }
}

// merged conv3: grid (GX,4); y<2 -> Wa -> outa (bf16, no bias), y>=2 -> Wb -> outb (f32 +biasb)
__global__ __launch_bounds__(256) void k_gemm_bf16s_2w(
    const float* __restrict__ A,
    const float* __restrict__ Wa, const float* __restrict__ Wb,
    const float* __restrict__ biasb,
    unsigned short* __restrict__ outa, float* __restrict__ outb,
    int M, int K,
    const float* __restrict__ bnsc, const float* __restrict__ bnsh)
{
  __shared__ __align__(16) short Ah[128*64];
  __shared__ __align__(16) short Al[128*64];
  __shared__ __align__(16) short Bh[64*64];
  __shared__ __align__(16) short Bl[64*64];
  const bool sel = blockIdx.y >= 2;
  const float* W = sel ? Wb : Wa;
  const int m0 = blockIdx.x*128, n0 = (blockIdx.y & 1)*64;
  const int t = threadIdx.x;
  const int lane = t & 63, wid = t >> 6;
  const int wm = wid >> 1, wn = wid & 1;

  f32x4 acc[4][2];
  #pragma unroll
  for(int i=0;i<4;i++)
    #pragma unroll
    for(int j=0;j<2;j++) acc[i][j] = (f32x4){0.f,0.f,0.f,0.f};

  const int ns1 = K >> 6;
  for(int s=0; s<ns1; ++s){
    int k0 = s*64;
    stage_A_bf16(A, K, k0, m0, M, t, bnsc, bnsh, Ah, Al, bnsc!=nullptr);
    stage_B_bf16(W, 128, k0, n0, t, Bh, Bl);
    __syncthreads();

    #pragma unroll
    for(int kk=0;kk<2;kk++){
      int kb = kk*32 + (lane>>4)*8;
      bf16x8 ahf[4], alf[4], bhf[2], blf[2];
      #pragma unroll
      for(int mf=0; mf<4; mf++){
        int r = wm*64 + mf*16 + (lane&15);
        int byte = (r*128 + kb*2) ^ ((r&7)<<4);
        ahf[mf] = *(const bf16x8*)((const char*)Ah + byte);
        alf[mf] = *(const bf16x8*)((const char*)Al + byte);
      }
      #pragma unroll
      for(int nf=0; nf<2; nf++){
        int n = wn*32 + nf*16 + (lane&15);
        int byte = (n*128 + kb*2) ^ ((n&7)<<4);
        bhf[nf] = *(const bf16x8*)((const char*)Bh + byte);
        blf[nf] = *(const bf16x8*)((const char*)Bl + byte);
      }
      #pragma unroll
      for(int mf=0; mf<4; mf++)
        #pragma unroll
        for(int nf=0; nf<2; nf++){
          acc[mf][nf] = __builtin_amdgcn_mfma_f32_16x16x32_bf16(ahf[mf], bhf[nf], acc[mf][nf], 0,0,0);
          acc[mf][nf] = __builtin_amdgcn_mfma_f32_16x16x32_bf16(ahf[mf], blf[nf], acc[mf][nf], 0,0,0);
          acc[mf][nf] = __builtin_amdgcn_mfma_f32_16x16x32_bf16(alf[mf], bhf[nf], acc[mf][nf], 0,0,0);
        }
    }
    __syncthreads();
  }

  #pragma unroll
  for(int mf=0; mf<4; mf++){
    #pragma unroll
    for(int nf=0; nf<2; nf++){
      int col = n0 + wn*32 + nf*16 + (lane&15);
      #pragma unroll
      for(int q=0;q<4;q++){
        int row = m0 + wm*64 + mf*16 + (lane>>4)*4 + q;
        if(row >= M) continue;
        if(sel){
          outb[(long)row*128 + col] = acc[mf][nf][q] + biasb[col];
        } else {
          outa[(long)row*128 + col] = f2bf(acc[mf][nf][q]);
        }
      }
    }
  }
}

// ---------------- conv1 GEMM in f64 (score-critical path) -------------------
// R9-verified: thread rows {tm, tm+16, tm+32, tm+48} -> conflict-free reads
// (SQ_LDS_BANK_CONFLICT = 0 measured); per-element FMA order fixed -> x1p
// bit-stable across rounds. Do NOT add launch_bounds min-waves (R11: VGPR
// forced to 48 -> f64 acc spilled to scratch, 130 MB FETCH, +30% time).
__global__ __launch_bounds__(256) void k_gemm_c1(
    const double* __restrict__ A1, const float* __restrict__ X,
    const float* __restrict__ W1, const float* __restrict__ W2,
    const float* __restrict__ bias, double* __restrict__ out, int M)
{
  __shared__ double Asd[32*67];
  __shared__ float  Wsf[32*66];
  const int m0 = blockIdx.x*64, n0 = blockIdx.y*64;
  const int t = threadIdx.x;
  const int tm = t & 15, tn = t >> 4;
  double acc[4][4];
  #pragma unroll
  for(int i=0;i<4;i++)
    #pragma unroll
    for(int j=0;j<4;j++) acc[i][j]=0.0;

  for(int pair=0; pair<2; pair++){
    const float* Wp = pair ? W2 : W1;
    for(int k0=0; k0<64; k0+=32){
      #pragma unroll
      for(int i=0;i<8;i++){
        int idx = t + i*256;
        int r = idx >> 5, c = idx & 31;
        int gr = m0 + r;
        double v = 0.0;
        if(gr<M) v = pair ? (double)X[(long)gr*64 + k0 + c] : A1[(long)gr*64 + k0 + c];
        Asd[c*67 + r] = v;
      }
      #pragma unroll
      for(int i=0;i<8;i++){
        int idx = t + i*256;
        int kk = idx >> 6, n = idx & 63;
        Wsf[kk*66 + n] = Wp[(k0+kk)*128 + n0 + n];
      }
      __syncthreads();
      #pragma unroll
      for(int kk=0;kk<32;kk++){
        double a0=Asd[kk*67 + tm],    a1=Asd[kk*67 + tm+16];
        double a2=Asd[kk*67 + tm+32], a3=Asd[kk*67 + tm+48];
        double w0=(double)Wsf[kk*66 + tn*4+0], w1=(double)Wsf[kk*66 + tn*4+1];
        double w2=(double)Wsf[kk*66 + tn*4+2], w3=(double)Wsf[kk*66 + tn*4+3];
        acc[0][0] += a0*w0; acc[0][1] += a0*w1; acc[0][2] += a0*w2; acc[0][3] += a0*w3;
        acc[1][0] += a1*w0; acc[1][1] += a1*w1; acc[1][2] += a1*w2; acc[1][3] += a1*w3;
        acc[2][0] += a2*w0; acc[2][1] += a2*w1; acc[2][2] += a2*w2; acc[2][3] += a2*w3;
        acc[3][0] += a3*w0; acc[3][1] += a3*w1; acc[3][2] += a3*w2; acc[3][3] += a3*w3;
      }
      __syncthreads();
    }
  }
  #pragma unroll
  for(int i=0;i<4;i++){
    int gr = m0 + tm + 16*i;
    if(gr>=M) continue;
    #pragma unroll
    for(int j=0;j<4;j++){
      int gc = n0 + tn*4 + j;
      double v = acc[i][j] + (double)bias[gc];
      if(v<0.0) v=0.0;
      out[(long)gr*128 + gc] = v;
    }
  }
}

// ---------------- Wt-fold: Wc = Wt @ Wd1[64:], bc = bd1 + bt @ Wd1[64:] -----
__global__ void k_wfold(const float* __restrict__ Wt, const float* __restrict__ bt,
                        const float* __restrict__ Wd1, const float* __restrict__ bd1,
                        float* __restrict__ Wc, float* __restrict__ bc){
  int j = threadIdx.x;
  int i = blockIdx.x;
  float s;
  if(i < 128){
    s = 0.f;
    for(int k=0;k<64;k++) s += Wt[i*64+k] * Wd1[(64+k)*128 + j];
    Wc[i*128+j] = s;
  } else {
    s = bd1[j];
    for(int k=0;k<64;k++) s += bt[k] * Wd1[(64+k)*128 + j];
    bc[j] = s;
  }
}

// ---------------- batchnorm ----------------
template<typename T>
__global__ void k_colstats(const T* __restrict__ x, int M, int J,
                           double* __restrict__ ps, double* __restrict__ pq){
  int c = threadIdx.x; int b = blockIdx.x, B = gridDim.x;
  int rows = (M + B - 1)/B;
  int r0 = b*rows, r1 = r0+rows; if(r1>M) r1=M;
  double s=0.0,q=0.0;
  for(int r=r0;r<r1;r++){ double v = (double)x[(long)r*J + c]; s+=v; q+=v*v; }
  ps[(long)b*J+c]=s; pq[(long)b*J+c]=q;
}

__global__ void k_bnfinal(const double* __restrict__ ps, const double* __restrict__ pq,
                          int B, int J, int M, const float* __restrict__ g,
                          const float* __restrict__ bta,
                          double* __restrict__ sc, double* __restrict__ sh,
                          float* __restrict__ sc32, float* __restrict__ sh32){
  int c = threadIdx.x; if(c>=J) return;
  double s=0.0,q=0.0;
  for(int b=0;b<B;b++){ s+=ps[(long)b*J+c]; q+=pq[(long)b*J+c]; }
  double m = s/M; double v = q/M - m*m;
  double inv = 1.0/sqrt(v + 1e-5);
  double a = (double)g[c]*inv;
  sc[c]=a; sh[c]=(double)bta[c] - m*a;
  sc32[c]=(float)a; sh32[c]=(float)((double)bta[c] - m*a);
}

// fused BN-apply + pooling dot terms + bf16 mirror (wave per node)
__global__ void k_bntr(const double* __restrict__ xp,
                       const double* __restrict__ sc, const double* __restrict__ sh,
                       const float* __restrict__ wrel, const float* __restrict__ wroot,
                       float* __restrict__ o32, unsigned short* __restrict__ obf,
                       double* __restrict__ t, double* __restrict__ r, int n){
  int gid = blockIdx.x*blockDim.x + threadIdx.x;
  int node = gid>>6, lane = gid&63;
  if(node>=n) return;
  long base = (long)node*128;
  double v0 = xp[base+lane]   *sc[lane]    + sh[lane];
  double v1 = xp[base+lane+64]*sc[lane+64] + sh[lane+64];
  float f0 = (float)v0, f1 = (float)v1;
  o32[base+lane]    = f0;
  o32[base+lane+64] = f1;
  obf[base+lane]    = f2bf(f0);
  obf[base+lane+64] = f2bf(f1);
  double tv = v0*(double)wrel[lane]  + v1*(double)wrel[lane+64];
  double rv = v0*(double)wroot[lane] + v1*(double)wroot[lane+64];
  for(int off=32; off>0; off>>=1){
    tv += __shfl_xor(tv, off);
    rv += __shfl_xor(rv, off);
  }
  if(lane==0){ t[node]=tv; r[node]=rv; }
}

// ---------------- z = mean + exp(log_std) * noise.mean(0), float4 ----------------
__global__ void k_z(const float* __restrict__ mean, const float* __restrict__ lstd,
                    const float* __restrict__ noise, float* __restrict__ z, int total4){
  int i = blockIdx.x*blockDim.x + threadIdx.x;
  if(i>=total4) return;
  const float4* m4 = (const float4*)mean;
  const float4* l4 = (const float4*)lstd;
  const float4* n4 = (const float4*)noise;
  float4 m = m4[i], l = l4[i];
  float nx=0.f, ny=0.f, nz=0.f, nw=0.f;
  #pragma unroll
  for(int s=0;s<10;s++){
    float4 v = n4[(long)s*total4 + i];
    nx+=v.x; ny+=v.y; nz+=v.z; nw+=v.w;
  }
  float4 o;
  o.x = (float)((double)m.x + exp((double)l.x)*((double)nx*0.1));
  o.y = (float)((double)m.y + exp((double)l.y)*((double)ny*0.1));
  o.z = (float)((double)m.z + exp((double)l.z)*((double)nz*0.1));
  o.w = (float)((double)m.w + exp((double)l.w)*((double)nw*0.1));
  ((float4*)z)[i] = o;
}

__global__ void k_score(const double* __restrict__ t, const double* __restrict__ r,
                        const int* __restrict__ csr, const int* __restrict__ rowptr,
                        const float* __restrict__ bp,
                        unsigned long long* __restrict__ key, int n){
  int i = blockIdx.x*blockDim.x + threadIdx.x;
  if(i>=n) return;
  double s = (double)bp[0] + r[i];
  int b=rowptr[i], e=rowptr[i+1];
  for(int j=b;j<e;j++) s += t[csr[j]];
  double sc = tanh(s) + 0.0;           // -0 -> +0
  long long u = __double_as_longlong(sc);
  unsigned long long uu = (unsigned long long)u;
  key[i] = (u < 0) ? ~uu : (uu ^ 0x8000000000000000ULL);
}

// ---- splitter-bucketed exact rank ----
__global__ void k_sample_sort(const unsigned long long* __restrict__ key,
                              unsigned long long* __restrict__ samp){
  __shared__ unsigned long long sm[NSAMP];
  int t = threadIdx.x;
  sm[t] = key[t*48];
  __syncthreads();
  for(int k=2; k<=NSAMP; k<<=1){
    for(int j=k>>1; j>0; j>>=1){
      int l = t ^ j;
      if(l > t){
        unsigned long long a = sm[t], b = sm[l];
        bool up = ((t & k) == 0);
        if(up ? (a > b) : (a < b)){ sm[t]=b; sm[l]=a; }
      }
      __syncthreads();
    }
  }
  samp[t] = sm[t];
}

__global__ __launch_bounds__(256) void k_bucket_assign(
    const unsigned long long* __restrict__ key,
    const unsigned long long* __restrict__ samp,
    int* __restrict__ bucket, int* __restrict__ bcnt, int n){
  __shared__ unsigned long long sm[NSAMP];
  for(int u=threadIdx.x; u<NSAMP; u+=256) sm[u] = samp[u];
  __syncthreads();
  int i = blockIdx.x*256 + threadIdx.x;
  if(i>=n) return;
  unsigned long long ki = key[i];
  int lo=0, hi=NSAMP;
  while(lo<hi){ int mid=(lo+hi)>>1; if(sm[mid] < ki) lo=mid+1; else hi=mid; }
  bucket[i]=lo;
  atomicAdd(&bcnt[lo],1);
}

__global__ void k_bucket_fill(const int* __restrict__ bucket,
                              const int* __restrict__ bstart, int* __restrict__ bfill,
                              int* __restrict__ blist, int n){
  int i = blockIdx.x*blockDim.x + threadIdx.x;
  if(i>=n) return;
  int b = bucket[i];
  int p = bstart[b] + atomicAdd(&bfill[b],1);
  blist[p] = i;
}

__global__ __launch_bounds__(256) void k_bucket_rank(
    const unsigned long long* __restrict__ key,
    const int* __restrict__ blist, const int* __restrict__ bstart,
    int n, int k, int* __restrict__ keep, int* __restrict__ perm){
  __shared__ unsigned long long skey[2048];
  __shared__ int sidx[2048];
  int b = blockIdx.x;
  int s0 = bstart[b], s1 = bstart[b+1];
  int m = s1 - s0;
  if(m<=0) return;
  int above = n - s1;
  if(m <= 2048){
    for(int u=threadIdx.x; u<m; u+=256){ int ii=blist[s0+u]; sidx[u]=ii; skey[u]=key[ii]; }
    __syncthreads();
    for(int u=threadIdx.x; u<m; u+=256){
      unsigned long long ki = skey[u]; int ii = sidx[u];
      int c = 0;
      for(int v=0; v<m; v++){
        unsigned long long kv = skey[v];
        c += ((kv > ki) || (kv == ki && sidx[v] < ii)) ? 1 : 0;
      }
      int rank = above + c;
      int kp = (rank < k) ? 1 : 0;
      keep[ii] = kp;
      if(kp) perm[rank] = ii;
    }
  } else {
    for(int u=threadIdx.x; u<m; u+=256){
      int ii = blist[s0+u];
      unsigned long long ki = key[ii];
      int c=0;
      for(int v=0; v<m; v++){
        int jj = blist[s0+v];
        unsigned long long kv = key[jj];
        c += ((kv > ki) || (kv == ki && jj < ii)) ? 1 : 0;
      }
      int rank = above + c;
      int kp = (rank < k) ? 1 : 0;
      keep[ii] = kp;
      if(kp) perm[rank] = ii;
    }
  }
}

__global__ void k_unpool(const float* __restrict__ x1, const int* __restrict__ perm,
                         float* __restrict__ out, int k){
  int i = blockIdx.x*blockDim.x + threadIdx.x;
  if(i >= k*128) return;
  int r = i>>7, c = i&127;
  out[i] = x1[(long)perm[r]*128 + c];
}

__global__ void k_edgeout(const int* __restrict__ src, const int* __restrict__ dst,
                          const int* __restrict__ keep, float* __restrict__ o2,
                          float* __restrict__ o3, int E){
  int e = blockIdx.x*blockDim.x + threadIdx.x;
  if(e>=E) return;
  int s=src[e], d=dst[e];
  bool m = keep[s] && keep[d];
  o2[e]   = m ? (float)s : -1.f;
  o2[E+e] = m ? (float)d : -1.f;
  o3[e]   = m ? 1.f : 0.f;
}

// ---------------- launch ----------------
extern "C" void kernel_launch(void* const* d_in, const int* in_sizes, int n_in,
                              void* d_out, int out_size, void* d_ws, size_t ws_size,
                              hipStream_t stream){
  const float* x     = (const float*)d_in[0];
  const int*   ei    = (const int*)d_in[1];
  const float* noise = (const float*)d_in[3];
  const float* We1l  = (const float*)d_in[4];
  const float* be1   = (const float*)d_in[5];
  const float* We1r  = (const float*)d_in[6];
  const float* g1    = (const float*)d_in[7];
  const float* b1    = (const float*)d_in[8];
  const float* We2l  = (const float*)d_in[9];
  const float* be2   = (const float*)d_in[10];
  const float* We2r  = (const float*)d_in[11];
  const float* g2    = (const float*)d_in[12];
  const float* b2    = (const float*)d_in[13];
  const float* We3l  = (const float*)d_in[14];
  const float* be3   = (const float*)d_in[15];
  const float* We3r  = (const float*)d_in[16];
  const float* Wt    = (const float*)d_in[17];
  const float* bt    = (const float*)d_in[18];
  const float* Wd1   = (const float*)d_in[19];
  const float* bd1   = (const float*)d_in[20];
  const float* gd    = (const float*)d_in[21];
  const float* bd    = (const float*)d_in[22];
  const float* Wd2   = (const float*)d_in[23];
  const float* bd2   = (const float*)d_in[24];
  const float* Wprel = (const float*)d_in[25];
  const float* bp    = (const float*)d_in[26];
  const float* Wproot= (const float*)d_in[27];

  const int* src = ei;
  const int* dst = ei + EE;

  float* out   = (float*)d_out;
  float* o_rec  = out;                 // N*64
  float* o_xun  = out + 3200000;       // k*128
  float* o_eiu  = out + 6400000;       // 2*E
  float* o_mask = out + 8000000;       // E
  float* o_mean = out + 8800000;       // N*64
  float* o_lstd = out + 12000000;      // N*64
  float* o_x1   = out + 15200000;      // N*128

  char* w = (char*)d_ws;
  size_t off = 0;
  auto alloc = [&](size_t bytes)->char*{
    char* p = w + off; off += (bytes + 255) & ~(size_t)255; return p;
  };
  int*    csr  = (int*)   alloc((size_t)EE*4);
  int*    rowp = (int*)   alloc((size_t)(NN+1)*4);
  int*    cnt  = (int*)   alloc((size_t)NN*4);
  char*   B3   =          alloc((size_t)NN*128*8);
  char*   B4   =          alloc((size_t)NN*64*8);
  char*   B5   =          alloc((size_t)NN*256*4);
  double* t_   = (double*)alloc((size_t)NN*8);
  double* r_   = (double*)alloc((size_t)NN*8);
  unsigned long long* key_ = (unsigned long long*)alloc((size_t)NN*8);
  int*    keep = (int*)   alloc((size_t)NN*4);
  int*    perm = (int*)   alloc((size_t)KHALF*4);
  double* ps   = (double*)alloc((size_t)240*256*8);
  double* pq   = (double*)alloc((size_t)240*256*8);
  double* bnsc = (double*)alloc(256*8);
  double* bnsh = (double*)alloc(256*8);
  float*  sc1f = (float*) alloc(256*4);
  float*  sh1f = (float*) alloc(256*4);
  float*  sc2f = (float*) alloc(256*4);
  float*  sh2f = (float*) alloc(256*4);
  float*  scdf = (float*) alloc(256*4);
  float*  shdf = (float*) alloc(256*4);
  float*  Wc   = (float*) alloc((size_t)128*128*4);
  float*  bc   = (float*) alloc(128*4);
  unsigned long long* samp = (unsigned long long*)alloc((size_t)NSAMP*8);
  int*    bucket = (int*) alloc((size_t)NN*4);
  int*    bcnt   = (int*) alloc((size_t)NBK*4);
  int*    bstart = (int*) alloc((size_t)(NBK+1)*4);
  int*    bfill  = (int*) alloc((size_t)NBK*4);
  int*    blist  = (int*) alloc((size_t)NN*4);
  (void)in_sizes; (void)n_in; (void)out_size; (void)ws_size;

  double* A1  = (double*)B4;
  double* x1p = (double*)B3;
  float*  A2  = (float*)B4;
  float*  x2  = (float*)B3;
  // B5 layout: [0, 12.8MB) = x1bf (bf16, conv1->conv2 phase) THEN T3 (bf16, conv3 phase)
  //            [25.6MB, 51.2MB) = msr (f32, conv3 phase); zb reuses [0,12.8MB) afterwards
  unsigned short* x1bf = (unsigned short*)B5;
  unsigned short* T3   = (unsigned short*)B5;
  float*  msr = (float*)(B5 + (size_t)NN*128*4);
  float*  zb  = (float*)B5;
  float*  h   = (float*)B4;

  const int GX = (NN+127)/128;   // 391

  // CSR build + weight fold (independent)
  hipMemsetAsync(cnt, 0, (size_t)NN*4, stream);
  k_hist<<<(EE+255)/256,256,0,stream>>>(dst, cnt, EE);
  k_wfold<<<129,128,0,stream>>>(Wt, bt, Wd1, bd1, Wc, bc);
  k_scan<<<1,1024,0,stream>>>(cnt, rowp, NN);
  hipMemsetAsync(cnt, 0, (size_t)NN*4, stream);
  k_fill<<<(EE+255)/256,256,0,stream>>>(src, dst, rowp, cnt, csr, EE);

  // conv1 (f64 score-critical path; bit-identical arithmetic)
  k_segmean<double,double,64,1><<<(NN+3)/4,256,0,stream>>>(x, csr, rowp, A1, NN);
  { dim3 g((NN+63)/64, 2);
    k_gemm_c1<<<g,256,0,stream>>>(A1, x, We1l, We1r, be1, x1p, NN); }
  k_colstats<double><<<240,128,0,stream>>>(x1p, NN, 128, ps, pq);
  k_bnfinal<<<1,128,0,stream>>>(ps,pq,240,128,NN,g1,b1,bnsc,bnsh,sc1f,sh1f);
  k_bntr<<<(NN+3)/4,256,0,stream>>>(x1p, bnsc, bnsh, Wprel, Wproot, o_x1, x1bf, t_, r_, NN);

  // conv2 (bf16x3 MFMA); gather from bf16 mirror of x1
  k_segmean_bf<<<(NN+3)/4,256,0,stream>>>(x1bf, csr, rowp, A2, NN);
  { dim3 g(GX, 4);
    k_gemm_bf16s<<<g,256,0,stream>>>(A2, We2l, 128, o_x1, We2r, 128, be2, x2, NN, 256, 1, nullptr, nullptr); }
  k_colstats<float><<<240,256,0,stream>>>(x2, NN, 256, ps, pq);
  k_bnfinal<<<1,256,0,stream>>>(ps,pq,240,256,NN,g2,b2,bnsc,bnsh,sc2f,sh2f);

  // conv3 transform-first, merged dual-weight launch; T3 emitted as bf16
  { dim3 g(GX, 4);
    k_gemm_bf16s_2w<<<g,256,0,stream>>>(x2, We3l, We3r, be3, T3, msr, NN, 256, sc2f, sh2f); }
  k_segmean_ms<<<(NN+3)/4,256,0,stream>>>(T3, msr, csr, rowp, o_mean, o_lstd, NN);

  // decoder: z, then fused h = relu(z@Wd1_top + x1@Wc + bc)
  k_z<<<(800000+255)/256,256,0,stream>>>(o_mean, o_lstd, noise, zb, 800000);
  { dim3 g(GX, 2);
    k_gemm_bf16s<<<g,256,0,stream>>>(zb, Wd1, 64, o_x1, Wc, 128, bc, h, NN, 128, 1, nullptr, nullptr); }
  k_colstats<float><<<240,128,0,stream>>>(h, NN, 128, ps, pq);
  k_bnfinal<<<1,128,0,stream>>>(ps,pq,240,128,NN,gd,bd,bnsc,bnsh,scdf,shdf);
  { dim3 g(GX, 1);
    k_gemm_bf16s<<<g,256,0,stream>>>(h, Wd2, 128, nullptr, nullptr, 0, bd2, o_rec, NN, 64, 0, scdf, shdf); }

  // pooling: score/key -> splitter-bucketed exact rank -> outputs
  k_score<<<(NN+255)/256,256,0,stream>>>(t_, r_, csr, rowp, bp, key_, NN);
  k_sample_sort<<<1,1024,0,stream>>>(key_, samp);
  hipMemsetAsync(bcnt, 0, (size_t)NBK*4, stream);
  k_bucket_assign<<<(NN+255)/256,256,0,stream>>>(key_, samp, bucket, bcnt, NN);
  k_scan<<<1,1024,0,stream>>>(bcnt, bstart, NBK);
  hipMemsetAsync(bfill, 0, (size_t)NBK*4, stream);
  k_bucket_fill<<<(NN+255)/256,256,0,stream>>>(bucket, bstart, bfill, blist, NN);
  k_bucket_rank<<<NBK,256,0,stream>>>(key_, blist, bstart, NN, KHALF, keep, perm);
  k_unpool<<<(KHALF*128+255)/256,256,0,stream>>>(o_x1, perm, o_xun, KHALF);
  k_edgeout<<<(EE+255)/256,256,0,stream>>>(src, dst, keep, o_eiu, o_mask, EE);
}